// Round 2
// baseline (685.323 us; speedup 1.0000x reference)
//
#include <hip/hip_runtime.h>

// Problem constants (from reference)
#define Nn 50000
#define Ee 1600000
#define INC 128
#define HID 128
#define OUTC 64

// ---------------------------------------------------------------------------
// CSR build: histogram -> exclusive scan (3 kernels) -> scatter by cursor
// ---------------------------------------------------------------------------

__global__ void hist_kernel(const int* __restrict__ dst, int* __restrict__ counts) {
    int e = blockIdx.x * blockDim.x + threadIdx.x;
    if (e < Ee) atomicAdd(&counts[dst[e]], 1);
}

__global__ void scan1_kernel(const int* __restrict__ counts, int* __restrict__ offsets,
                             int* __restrict__ partials) {
    __shared__ int sd[256];
    int t = threadIdx.x;
    int i = blockIdx.x * 256 + t;
    int c = (i < Nn) ? counts[i] : 0;
    int v = c;
    #pragma unroll
    for (int off = 1; off < 256; off <<= 1) {
        sd[t] = v; __syncthreads();
        int add = (t >= off) ? sd[t - off] : 0;
        __syncthreads();
        v += add;
    }
    if (i < Nn) offsets[i] = v - c;          // exclusive within block
    if (t == 255) partials[blockIdx.x] = v;  // block total
}

__global__ void scan2_kernel(const int* __restrict__ partials, int* __restrict__ pbase, int nb) {
    __shared__ int sd[256];
    int t = threadIdx.x;
    int c = (t < nb) ? partials[t] : 0;
    int v = c;
    #pragma unroll
    for (int off = 1; off < 256; off <<= 1) {
        sd[t] = v; __syncthreads();
        int add = (t >= off) ? sd[t - off] : 0;
        __syncthreads();
        v += add;
    }
    if (t < nb) pbase[t] = v - c;            // exclusive over blocks
}

__global__ void scan3_kernel(int* __restrict__ offsets, const int* __restrict__ pbase,
                             const int* __restrict__ counts, int* __restrict__ cursor,
                             float* __restrict__ dis) {
    int i = blockIdx.x * 256 + threadIdx.x;
    if (i == 0) offsets[Nn] = Ee;
    if (i < Nn) {
        int off = offsets[i] + pbase[blockIdx.x];
        offsets[i] = off;
        cursor[i]  = off;
        dis[i]     = rsqrtf((float)(counts[i] + 1));  // +1 self-loop; deg>=1 always
    }
}

__global__ void fill_csr_kernel(const int* __restrict__ ei, int* __restrict__ cursor,
                                int* __restrict__ csr_src) {
    int e = blockIdx.x * blockDim.x + threadIdx.x;
    if (e < Ee) {
        int s = ei[e];
        int d = ei[Ee + e];
        int pos = atomicAdd(&cursor[d], 1);
        csr_src[pos] = s;
    }
}

// ---------------------------------------------------------------------------
// Propagation: one 64-lane wave per node. acc = dis_i^2*h[i] + sum dis_s*dis_i*h[s]
// then + bias (, relu). Row reads are float2/lane = 512B coalesced per row.
// Edge loop unrolled x4 with up-front index/weight/row loads: 4 gather chains
// in flight per wave (MLP) instead of 1 dependent chain.
// ---------------------------------------------------------------------------

template <bool RELU>
__global__ __launch_bounds__(256) void propagate_kernel(
    const float* __restrict__ h, const int* __restrict__ offs,
    const int* __restrict__ csr, const float* __restrict__ dis,
    const float* __restrict__ bias, float* __restrict__ out) {
    int node = blockIdx.x * 4 + (threadIdx.x >> 6);
    if (node >= Nn) return;
    int lane = threadIdx.x & 63;
    float di = dis[node];
    float2 hv = *((const float2*)(h + (size_t)node * 128) + lane);
    float w0 = di * di;
    float ax = w0 * hv.x, ay = w0 * hv.y;
    int beg = offs[node], end = offs[node + 1];
    int e = beg;
    for (; e + 4 <= end; e += 4) {
        int s0 = csr[e], s1 = csr[e + 1], s2 = csr[e + 2], s3 = csr[e + 3];
        float q0 = dis[s0], q1 = dis[s1], q2 = dis[s2], q3 = dis[s3];
        float2 v0 = *((const float2*)(h + (size_t)s0 * 128) + lane);
        float2 v1 = *((const float2*)(h + (size_t)s1 * 128) + lane);
        float2 v2 = *((const float2*)(h + (size_t)s2 * 128) + lane);
        float2 v3 = *((const float2*)(h + (size_t)s3 * 128) + lane);
        float u0 = di * q0, u1 = di * q1, u2 = di * q2, u3 = di * q3;
        ax = fmaf(u0, v0.x, ax); ay = fmaf(u0, v0.y, ay);
        ax = fmaf(u1, v1.x, ax); ay = fmaf(u1, v1.y, ay);
        ax = fmaf(u2, v2.x, ax); ay = fmaf(u2, v2.y, ay);
        ax = fmaf(u3, v3.x, ax); ay = fmaf(u3, v3.y, ay);
    }
    for (; e < end; ++e) {
        int s = csr[e];
        float w = di * dis[s];
        float2 v = *((const float2*)(h + (size_t)s * 128) + lane);
        ax = fmaf(w, v.x, ax);
        ay = fmaf(w, v.y, ay);
    }
    ax += bias[lane * 2];
    ay += bias[lane * 2 + 1];
    if (RELU) { ax = fmaxf(ax, 0.f); ay = fmaxf(ay, 0.f); }
    *((float2*)(out + (size_t)node * 128) + lane) = make_float2(ax, ay);
}

// ---------------------------------------------------------------------------
// GEMM: OUT[N][CO] = act(concat(A0,A1) @ W^T + bias), W is [CO][K] row-major.
// Tile: 32 rows x CO cols per 256-thread block; K chunked by 64.
// Per-thread micro-tile: 4 rows x CPT cols (CPT=4 for CO=128, 2 for CO=64).
// ---------------------------------------------------------------------------

template <int CO, int K, bool RELU, bool HASBIAS>
__global__ __launch_bounds__(256) void gemm_kernel(
    const float* __restrict__ A0, const float* __restrict__ A1,
    const float* __restrict__ W, const float* __restrict__ bias,
    float* __restrict__ out) {
    constexpr int KC  = 64;
    constexpr int CPT = (CO == 128) ? 4 : 2;
    __shared__ float At[32][KC + 4];
    __shared__ float Wt[KC][CO + 4];

    int t  = threadIdx.x;
    int cg = t & 31, rg = t >> 5;
    int c0 = cg * CPT, r0 = rg * 4;
    int row0 = blockIdx.x * 32;

    float acc[4][CPT];
    #pragma unroll
    for (int i = 0; i < 4; ++i)
        #pragma unroll
        for (int j = 0; j < CPT; ++j) acc[i][j] = 0.f;

    for (int k0 = 0; k0 < K; k0 += KC) {
        const float* src = (K == 256 && k0 >= 128) ? A1 : A0;
        int kb = (K == 256 && k0 >= 128) ? (k0 - 128) : k0;
        // stage A tile: 32 rows x 64 cols = 512 float4, 2 per thread
        #pragma unroll
        for (int i = 0; i < 2; ++i) {
            int f4 = t + i * 256;
            int r = f4 >> 4, kk = (f4 & 15) * 4;
            int row = row0 + r;
            float4 v = make_float4(0.f, 0.f, 0.f, 0.f);
            if (row < Nn) v = *(const float4*)(src + (size_t)row * 128 + kb + kk);
            *(float4*)&At[r][kk] = v;
        }
        // stage W chunk transposed: Wt[kk][c]
        constexpr int WF4 = CO * 16 / 256;
        #pragma unroll
        for (int i = 0; i < WF4; ++i) {
            int f4 = t + i * 256;
            int c = f4 >> 4, kk = (f4 & 15) * 4;
            float4 wv = *(const float4*)(W + (size_t)c * K + k0 + kk);
            Wt[kk + 0][c] = wv.x;
            Wt[kk + 1][c] = wv.y;
            Wt[kk + 2][c] = wv.z;
            Wt[kk + 3][c] = wv.w;
        }
        __syncthreads();
        #pragma unroll 8
        for (int kk = 0; kk < KC; ++kk) {
            float a[4];
            #pragma unroll
            for (int i = 0; i < 4; ++i) a[i] = At[r0 + i][kk];
            float w[CPT];
            #pragma unroll
            for (int j = 0; j < CPT; ++j) w[j] = Wt[kk][c0 + j];
            #pragma unroll
            for (int i = 0; i < 4; ++i)
                #pragma unroll
                for (int j = 0; j < CPT; ++j) acc[i][j] = fmaf(a[i], w[j], acc[i][j]);
        }
        __syncthreads();
    }

    #pragma unroll
    for (int i = 0; i < 4; ++i) {
        int row = row0 + r0 + i;
        if (row < Nn) {
            #pragma unroll
            for (int j = 0; j < CPT; ++j) {
                float v = acc[i][j];
                if (HASBIAS) v += bias[c0 + j];
                if (RELU) v = fmaxf(v, 0.f);
                out[(size_t)row * CO + c0 + j] = v;
            }
        }
    }
}

// ---------------------------------------------------------------------------

extern "C" void kernel_launch(void* const* d_in, const int* in_sizes, int n_in,
                              void* d_out, int out_size, void* d_ws, size_t ws_size,
                              hipStream_t stream) {
    const float* x  = (const float*)d_in[0];
    const int*   ei = (const int*)d_in[1];   // [2][E]: src then dst
    const float* W1 = (const float*)d_in[2];
    const float* b1 = (const float*)d_in[3];
    const float* Wc = (const float*)d_in[4];
    const float* bc = (const float*)d_in[5];
    const float* W2 = (const float*)d_in[6];
    const float* b2 = (const float*)d_in[7];
    const float* Wo = (const float*)d_in[8];
    const float* bo = (const float*)d_in[9];
    float* out = (float*)d_out;

    // workspace carve-up (256B aligned)
    char* base = (char*)d_ws;
    auto carve = [&](size_t bytes) {
        void* p = (void*)base;
        base += (bytes + 255) & ~(size_t)255;
        return p;
    };
    int*   counts   = (int*)carve(Nn * sizeof(int));
    int*   offsets  = (int*)carve((Nn + 1) * sizeof(int));
    int*   cursor   = (int*)carve(Nn * sizeof(int));
    int*   partials = (int*)carve(256 * sizeof(int));
    int*   pbase    = (int*)carve(256 * sizeof(int));
    float* dis      = (float*)carve(Nn * sizeof(float));
    int*   csr      = (int*)carve(Ee * sizeof(int));
    float* bufA     = (float*)carve((size_t)Nn * 128 * sizeof(float));
    float* bufB     = (float*)carve((size_t)Nn * 128 * sizeof(float));
    float* bufC     = (float*)carve((size_t)Nn * 128 * sizeof(float));

    const int SCAN_BLOCKS = (Nn + 255) / 256;  // 196

    // --- CSR build ---
    hipMemsetAsync(counts, 0, Nn * sizeof(int), stream);
    hist_kernel<<<(Ee + 255) / 256, 256, 0, stream>>>(ei + Ee, counts);
    scan1_kernel<<<SCAN_BLOCKS, 256, 0, stream>>>(counts, offsets, partials);
    scan2_kernel<<<1, 256, 0, stream>>>(partials, pbase, SCAN_BLOCKS);
    scan3_kernel<<<SCAN_BLOCKS, 256, 0, stream>>>(offsets, pbase, counts, cursor, dis);
    fill_csr_kernel<<<(Ee + 255) / 256, 256, 0, stream>>>(ei, cursor, csr);

    const int GB128 = (Nn + 31) / 32;  // 1563
    const int PB    = (Nn + 3) / 4;    // 12500

    // h1 = x @ W1^T              -> bufA
    gemm_kernel<128, 128, false, false><<<GB128, 256, 0, stream>>>(x, nullptr, W1, nullptr, bufA);
    // x_agg = relu(prop(h1)+b1)  -> bufB
    propagate_kernel<true><<<PB, 256, 0, stream>>>(bufA, offsets, csr, dis, b1, bufB);
    // x_comb = relu([x_agg,x] @ Wc^T + bc) -> bufC
    gemm_kernel<128, 256, true, true><<<GB128, 256, 0, stream>>>(bufB, x, Wc, bc, bufC);
    // h2 = x_comb @ W2^T         -> bufA
    gemm_kernel<128, 128, false, false><<<GB128, 256, 0, stream>>>(bufC, nullptr, W2, nullptr, bufA);
    // agg2 = prop(h2)+b2         -> bufB
    propagate_kernel<false><<<PB, 256, 0, stream>>>(bufA, offsets, csr, dis, b2, bufB);
    // out = [agg2, x_comb] @ Wo^T + bo -> d_out
    gemm_kernel<64, 256, false, true><<<GB128, 256, 0, stream>>>(bufB, bufC, Wo, bo, out);
}

// Round 3
// 637.308 us; speedup vs baseline: 1.0753x; 1.0753x over previous
//
#include <hip/hip_runtime.h>

// Problem constants (from reference)
#define Nn 50000
#define Ee 1600000
#define INC 128
#define HID 128
#define OUTC 64
#define NPART 8
#define PART_SZ 6250   // Nn / NPART exactly

typedef __attribute__((ext_vector_type(8))) short short8;
typedef __attribute__((ext_vector_type(4))) float f32x4;
typedef unsigned short ushort;

// ---------------------------------------------------------------------------
// bf16 split helpers (RNE)
// ---------------------------------------------------------------------------
__device__ __forceinline__ ushort f32_to_bf16(float f) {
    unsigned u = __builtin_bit_cast(unsigned, f);
    unsigned r = u + 0x7FFFu + ((u >> 16) & 1u);
    return (ushort)(r >> 16);
}
__device__ __forceinline__ float bf16_to_f32(ushort h) {
    unsigned u = ((unsigned)h) << 16;
    return __builtin_bit_cast(float, u);
}

// ---------------------------------------------------------------------------
// CSR build: histogram -> exclusive scan -> XCD-partitioned scatter
// ---------------------------------------------------------------------------

__global__ void hist_kernel(const int* __restrict__ dst, int* __restrict__ counts) {
    int e = blockIdx.x * blockDim.x + threadIdx.x;
    if (e < Ee) atomicAdd(&counts[dst[e]], 1);
}

__global__ void scan1_kernel(const int* __restrict__ counts, int* __restrict__ offsets,
                             int* __restrict__ partials) {
    __shared__ int sd[256];
    int t = threadIdx.x;
    int i = blockIdx.x * 256 + t;
    int c = (i < Nn) ? counts[i] : 0;
    int v = c;
    #pragma unroll
    for (int off = 1; off < 256; off <<= 1) {
        sd[t] = v; __syncthreads();
        int add = (t >= off) ? sd[t - off] : 0;
        __syncthreads();
        v += add;
    }
    if (i < Nn) offsets[i] = v - c;
    if (t == 255) partials[blockIdx.x] = v;
}

__global__ void scan2_kernel(const int* __restrict__ partials, int* __restrict__ pbase, int nb) {
    __shared__ int sd[256];
    int t = threadIdx.x;
    int c = (t < nb) ? partials[t] : 0;
    int v = c;
    #pragma unroll
    for (int off = 1; off < 256; off <<= 1) {
        sd[t] = v; __syncthreads();
        int add = (t >= off) ? sd[t - off] : 0;
        __syncthreads();
        v += add;
    }
    if (t < nb) pbase[t] = v - c;
}

__global__ void scan3_kernel(int* __restrict__ offsets, const int* __restrict__ pbase,
                             const int* __restrict__ counts, int* __restrict__ cursor,
                             float* __restrict__ dis) {
    int i = blockIdx.x * 256 + threadIdx.x;
    if (i == 0) offsets[Nn] = Ee;
    if (i < Nn) {
        int off = offsets[i] + pbase[blockIdx.x];
        offsets[i] = off;
        cursor[i]  = off;
        dis[i]     = rsqrtf((float)(counts[i] + 1));  // +1 self-loop
    }
}

// Partitioned scatter: block b owns dst-range (b%8); under round-robin
// block->XCD mapping all writers of a csr line share one L2 -> full-line
// writebacks instead of 16x partial-dirty bounce. Edge list re-read 8x (L3).
__global__ __launch_bounds__(256) void fill_csr_part(const int* __restrict__ ei,
                                                     int* __restrict__ cursor,
                                                     int* __restrict__ csr) {
    int p     = blockIdx.x & (NPART - 1);
    int chunk = blockIdx.x >> 3;
    int nch   = gridDim.x >> 3;
    int lo = p * PART_SZ, hi = lo + PART_SZ;
    int per = (Ee + nch - 1) / nch;
    int e0 = chunk * per;
    int e1 = (e0 + per < Ee) ? e0 + per : Ee;
    const int* __restrict__ dst = ei + Ee;
    for (int e = e0 + threadIdx.x; e < e1; e += 256) {
        int d = dst[e];
        if (d >= lo && d < hi) {
            int pos = atomicAdd(&cursor[d], 1);
            csr[pos] = ei[e];
        }
    }
}

// ---------------------------------------------------------------------------
// Weight prep: split all 4 weight matrices into bf16 hi/lo planes.
// Element offsets inside plane base (ushort units):
//   w1hi@0 w1lo@16384 | wchi@32768 wclo@65536 | w2hi@98304 w2lo@114688
//   wohi@131072 wolo@147456   (total 163840 el = 320 KiB)
// ---------------------------------------------------------------------------
__global__ void prep_w_kernel(const float* __restrict__ W1, const float* __restrict__ Wc,
                              const float* __restrict__ W2, const float* __restrict__ Wo,
                              ushort* __restrict__ base) {
    int i = blockIdx.x * 256 + threadIdx.x;  // 0..81919
    const float* src; ushort* hi; ushort* lo; int idx;
    if (i < 16384)      { src = W1; hi = base;          lo = base + 16384;  idx = i; }
    else if (i < 49152) { src = Wc; hi = base + 32768;  lo = base + 65536;  idx = i - 16384; }
    else if (i < 65536) { src = W2; hi = base + 98304;  lo = base + 114688; idx = i - 49152; }
    else                { src = Wo; hi = base + 131072; lo = base + 147456; idx = i - 65536; }
    float f = src[idx];
    ushort hb = f32_to_bf16(f);
    float  hf = bf16_to_f32(hb);
    hi[idx] = hb;
    lo[idx] = f32_to_bf16(f - hf);
}

// ---------------------------------------------------------------------------
// MFMA GEMM: OUT[N][CO] = act(concat(A0,A1)[N][K] @ W^T + bias) (* dis[row])
// W given as bf16 hi/lo planes [CO][K]. f32 = hi + lo; C = A_hi*B_hi +
// A_hi*B_lo + A_lo*B_hi (rel err ~2^-17). Block = 4 waves; wave w owns rows
// [blk*64 + w*16, +16) x all CO cols. No LDS: A read once as float4 + in-reg
// split; W frags from global (L2-resident).
// mfma_f32_16x16x32_bf16 layout: A: lane(l) row=l&15, k=(l>>4)*8+j;
// B: col=l&15, k=(l>>4)*8+j; D: col=l&15, row=(l>>4)*4+reg.
// ---------------------------------------------------------------------------
template <int CO, int K, bool RELU, bool HASBIAS, bool SCALEDIS>
__global__ __launch_bounds__(256) void mfma_gemm(
    const float* __restrict__ A0, const float* __restrict__ A1,
    const ushort* __restrict__ Whi, const ushort* __restrict__ Wlo,
    const float* __restrict__ bias, const float* __restrict__ dis,
    float* __restrict__ out) {
    constexpr int NF = CO / 16;
    int wave = threadIdx.x >> 6;
    int lane = threadIdx.x & 63;
    int c = lane & 15;        // A row offset / D col offset
    int g = lane >> 4;        // k-group / D row-group
    int row0 = blockIdx.x * 64 + wave * 16;
    int arow = row0 + c;
    int ar = (arow < Nn) ? arow : (Nn - 1);

    f32x4 acc[NF];
    #pragma unroll
    for (int f = 0; f < NF; ++f) acc[f] = (f32x4){0.f, 0.f, 0.f, 0.f};

    #pragma unroll
    for (int ks = 0; ks < K / 32; ++ks) {
        int k0 = ks * 32;
        const float* Asrc = (K == 256 && k0 >= 128) ? A1 : A0;
        int kb = (K == 256 && k0 >= 128) ? (k0 - 128) : k0;
        const float* ap = Asrc + (size_t)ar * 128 + kb + g * 8;
        float4 v0 = *(const float4*)ap;
        float4 v1 = *(const float4*)(ap + 4);
        float vv[8] = {v0.x, v0.y, v0.z, v0.w, v1.x, v1.y, v1.z, v1.w};
        short8 ahi, alo;
        #pragma unroll
        for (int j = 0; j < 8; ++j) {
            float f = vv[j];
            ushort hb = f32_to_bf16(f);
            float  hf = bf16_to_f32(hb);
            ahi[j] = (short)hb;
            alo[j] = (short)f32_to_bf16(f - hf);
        }
        int wk = k0 + g * 8;
        #pragma unroll
        for (int f = 0; f < NF; ++f) {
            size_t widx = (size_t)(f * 16 + c) * K + wk;
            short8 bh = *(const short8*)(Whi + widx);
            short8 bl = *(const short8*)(Wlo + widx);
            acc[f] = __builtin_amdgcn_mfma_f32_16x16x32_bf16(alo, bh, acc[f], 0, 0, 0);
            acc[f] = __builtin_amdgcn_mfma_f32_16x16x32_bf16(ahi, bl, acc[f], 0, 0, 0);
            acc[f] = __builtin_amdgcn_mfma_f32_16x16x32_bf16(ahi, bh, acc[f], 0, 0, 0);
        }
    }

    #pragma unroll
    for (int f = 0; f < NF; ++f) {
        int col = f * 16 + c;
        float bv = HASBIAS ? bias[col] : 0.f;
        #pragma unroll
        for (int rg = 0; rg < 4; ++rg) {
            int row = row0 + g * 4 + rg;
            if (row < Nn) {
                float v = acc[f][rg] + bv;
                if (RELU) v = fmaxf(v, 0.f);
                if (SCALEDIS) v *= dis[row];
                out[(size_t)row * CO + col] = v;
            }
        }
    }
}

// ---------------------------------------------------------------------------
// Propagation in g-form (g = dis*h precomputed by GEMM epilogue):
// out[d] = act(dis[d] * (g[d] + sum_{s in N(d)} g[s]) + bias)
// One 64-lane wave per node, float2/lane rows, edge loop unrolled x4.
// ---------------------------------------------------------------------------
template <bool RELU>
__global__ __launch_bounds__(256) void propagate_kernel(
    const float* __restrict__ gbuf, const int* __restrict__ offs,
    const int* __restrict__ csr, const float* __restrict__ dis,
    const float* __restrict__ bias, float* __restrict__ out) {
    int node = blockIdx.x * 4 + (threadIdx.x >> 6);
    if (node >= Nn) return;
    int lane = threadIdx.x & 63;
    float2 sv = *((const float2*)(gbuf + (size_t)node * 128) + lane);  // self term
    float ax = sv.x, ay = sv.y;
    int beg = offs[node], end = offs[node + 1];
    int e = beg;
    for (; e + 4 <= end; e += 4) {
        int s0 = csr[e], s1 = csr[e + 1], s2 = csr[e + 2], s3 = csr[e + 3];
        float2 v0 = *((const float2*)(gbuf + (size_t)s0 * 128) + lane);
        float2 v1 = *((const float2*)(gbuf + (size_t)s1 * 128) + lane);
        float2 v2 = *((const float2*)(gbuf + (size_t)s2 * 128) + lane);
        float2 v3 = *((const float2*)(gbuf + (size_t)s3 * 128) + lane);
        ax += v0.x + v1.x + v2.x + v3.x;
        ay += v0.y + v1.y + v2.y + v3.y;
    }
    for (; e < end; ++e) {
        int s = csr[e];
        float2 v = *((const float2*)(gbuf + (size_t)s * 128) + lane);
        ax += v.x;
        ay += v.y;
    }
    float di = dis[node];
    ax = fmaf(di, ax, bias[lane * 2]);
    ay = fmaf(di, ay, bias[lane * 2 + 1]);
    if (RELU) { ax = fmaxf(ax, 0.f); ay = fmaxf(ay, 0.f); }
    *((float2*)(out + (size_t)node * 128) + lane) = make_float2(ax, ay);
}

// ---------------------------------------------------------------------------

extern "C" void kernel_launch(void* const* d_in, const int* in_sizes, int n_in,
                              void* d_out, int out_size, void* d_ws, size_t ws_size,
                              hipStream_t stream) {
    const float* x  = (const float*)d_in[0];
    const int*   ei = (const int*)d_in[1];   // [2][E]: src then dst
    const float* W1 = (const float*)d_in[2];
    const float* b1 = (const float*)d_in[3];
    const float* Wc = (const float*)d_in[4];
    const float* bc = (const float*)d_in[5];
    const float* W2 = (const float*)d_in[6];
    const float* b2 = (const float*)d_in[7];
    const float* Wo = (const float*)d_in[8];
    const float* bo = (const float*)d_in[9];
    float* out = (float*)d_out;

    // workspace carve-up (256B aligned)
    char* base = (char*)d_ws;
    auto carve = [&](size_t bytes) {
        void* p = (void*)base;
        base += (bytes + 255) & ~(size_t)255;
        return p;
    };
    // tmp region: counts+cursor live during CSR build; W bf16 planes alias it
    // afterwards (planes need 320KB < 400KB of dead counts+cursor space).
    char*  tmp      = (char*)carve(512 * 1024);
    int*   counts   = (int*)tmp;                    // 200000 B
    int*   cursor   = (int*)(tmp + 204800);         // 200000 B
    ushort* wplanes = (ushort*)tmp;                 // 327680 B, used after fill
    int*   offsets  = (int*)carve((Nn + 1) * sizeof(int));
    int*   partials = (int*)carve(256 * sizeof(int));
    int*   pbase    = (int*)carve(256 * sizeof(int));
    float* dis      = (float*)carve(Nn * sizeof(float));
    int*   csr      = (int*)carve(Ee * sizeof(int));
    float* bufA     = (float*)carve((size_t)Nn * 128 * sizeof(float));
    float* bufB     = (float*)carve((size_t)Nn * 128 * sizeof(float));
    float* bufC     = (float*)carve((size_t)Nn * 128 * sizeof(float));

    const ushort* w1hi = wplanes;
    const ushort* w1lo = wplanes + 16384;
    const ushort* wchi = wplanes + 32768;
    const ushort* wclo = wplanes + 65536;
    const ushort* w2hi = wplanes + 98304;
    const ushort* w2lo = wplanes + 114688;
    const ushort* wohi = wplanes + 131072;
    const ushort* wolo = wplanes + 147456;

    const int SCAN_BLOCKS = (Nn + 255) / 256;  // 196

    // --- CSR build ---
    hipMemsetAsync(counts, 0, Nn * sizeof(int), stream);
    hist_kernel<<<(Ee + 255) / 256, 256, 0, stream>>>(ei + Ee, counts);
    scan1_kernel<<<SCAN_BLOCKS, 256, 0, stream>>>(counts, offsets, partials);
    scan2_kernel<<<1, 256, 0, stream>>>(partials, pbase, SCAN_BLOCKS);
    scan3_kernel<<<SCAN_BLOCKS, 256, 0, stream>>>(offsets, pbase, counts, cursor, dis);
    fill_csr_part<<<NPART * 256, 256, 0, stream>>>(ei, cursor, csr);

    // --- weight prep (aliases dead counts/cursor space) ---
    prep_w_kernel<<<320, 256, 0, stream>>>(W1, Wc, W2, Wo, (ushort*)wplanes);

    const int GB = (Nn + 63) / 64;   // 782
    const int PB = (Nn + 3) / 4;     // 12500

    // g1 = dis * (x @ W1^T)                     -> bufA
    mfma_gemm<128, 128, false, false, true><<<GB, 256, 0, stream>>>(
        x, nullptr, w1hi, w1lo, nullptr, dis, bufA);
    // x_agg = relu(dis*(sum g1) + b1)           -> bufB
    propagate_kernel<true><<<PB, 256, 0, stream>>>(bufA, offsets, csr, dis, b1, bufB);
    // x_comb = relu([x_agg, x] @ Wc^T + bc)     -> bufC
    mfma_gemm<128, 256, true, true, false><<<GB, 256, 0, stream>>>(
        bufB, x, wchi, wclo, bc, nullptr, bufC);
    // g2 = dis * (x_comb @ W2^T)                -> bufA
    mfma_gemm<128, 128, false, false, true><<<GB, 256, 0, stream>>>(
        bufC, nullptr, w2hi, w2lo, nullptr, dis, bufA);
    // agg2 = dis*(sum g2) + b2                  -> bufB
    propagate_kernel<false><<<PB, 256, 0, stream>>>(bufA, offsets, csr, dis, b2, bufB);
    // out = [agg2, x_comb] @ Wo^T + bo          -> d_out
    mfma_gemm<64, 256, false, true, false><<<GB, 256, 0, stream>>>(
        bufB, bufC, wohi, wolo, bo, nullptr, out);
}

// Round 5
// 548.826 us; speedup vs baseline: 1.2487x; 1.1612x over previous
//
#include <hip/hip_runtime.h>
#include <hip/hip_fp16.h>

// Problem constants (from reference)
#define Nn 50000
#define Ee 1600000
#define INC 128
#define HID 128
#define OUTC 64
#define NPART 8
#define PART_SZ 6250   // Nn / NPART exactly

typedef __attribute__((ext_vector_type(8))) short short8;
typedef __attribute__((ext_vector_type(4))) float f32x4;
typedef unsigned short ushort;

// ---------------------------------------------------------------------------
// bf16 split helpers (RNE)
// ---------------------------------------------------------------------------
__device__ __forceinline__ ushort f32_to_bf16(float f) {
    unsigned u = __builtin_bit_cast(unsigned, f);
    unsigned r = u + 0x7FFFu + ((u >> 16) & 1u);
    return (ushort)(r >> 16);
}
__device__ __forceinline__ float bf16_to_f32(ushort h) {
    unsigned u = ((unsigned)h) << 16;
    return __builtin_bit_cast(float, u);
}

// ---------------------------------------------------------------------------
// CSR build: histogram -> exclusive scan -> XCD-partitioned scatter
// ---------------------------------------------------------------------------

__global__ void hist_kernel(const int* __restrict__ dst, int* __restrict__ counts) {
    int e = blockIdx.x * blockDim.x + threadIdx.x;
    if (e < Ee) atomicAdd(&counts[dst[e]], 1);
}

__global__ void scan1_kernel(const int* __restrict__ counts, int* __restrict__ offsets,
                             int* __restrict__ partials) {
    __shared__ int sd[256];
    int t = threadIdx.x;
    int i = blockIdx.x * 256 + t;
    int c = (i < Nn) ? counts[i] : 0;
    int v = c;
    #pragma unroll
    for (int off = 1; off < 256; off <<= 1) {
        sd[t] = v; __syncthreads();
        int add = (t >= off) ? sd[t - off] : 0;
        __syncthreads();
        v += add;
    }
    if (i < Nn) offsets[i] = v - c;
    if (t == 255) partials[blockIdx.x] = v;
}

// scan3 with scan2 folded in: every block computes its own base as the sum of
// partials[0..blockIdx.x) (196 values, one per thread, LDS tree-reduce).
__global__ void scan3_kernel(int* __restrict__ offsets, const int* __restrict__ partials,
                             const int* __restrict__ counts, int* __restrict__ cursor,
                             float* __restrict__ dis) {
    __shared__ int sd[256];
    int t = threadIdx.x;
    int s = (t < blockIdx.x) ? partials[t] : 0;   // blockIdx.x <= 195 < 256
    sd[t] = s; __syncthreads();
    #pragma unroll
    for (int off = 128; off > 0; off >>= 1) {
        if (t < off) sd[t] += sd[t + off];
        __syncthreads();
    }
    int base = sd[0];
    int i = blockIdx.x * 256 + t;
    if (i == 0) offsets[Nn] = Ee;
    if (i < Nn) {
        int off = offsets[i] + base;
        offsets[i] = off;
        cursor[i]  = off;
        dis[i]     = rsqrtf((float)(counts[i] + 1));  // +1 self-loop
    }
}

// Partitioned scatter: block b owns dst-range (b%8); under round-robin
// block->XCD mapping all writers of a csr line share one L2 -> full-line
// writebacks instead of 16x partial-dirty bounce.
__global__ __launch_bounds__(256) void fill_csr_part(const int* __restrict__ ei,
                                                     int* __restrict__ cursor,
                                                     int* __restrict__ csr) {
    int p     = blockIdx.x & (NPART - 1);
    int chunk = blockIdx.x >> 3;
    int nch   = gridDim.x >> 3;
    int lo = p * PART_SZ, hi = lo + PART_SZ;
    int per = (Ee + nch - 1) / nch;
    int e0 = chunk * per;
    int e1 = (e0 + per < Ee) ? e0 + per : Ee;
    const int* __restrict__ dst = ei + Ee;
    for (int e = e0 + threadIdx.x; e < e1; e += 256) {
        int d = dst[e];
        if (d >= lo && d < hi) {
            int pos = atomicAdd(&cursor[d], 1);
            csr[pos] = ei[e];
        }
    }
}

// ---------------------------------------------------------------------------
// Weight prep: split all 4 weight matrices into bf16 hi/lo planes.
// ---------------------------------------------------------------------------
__global__ void prep_w_kernel(const float* __restrict__ W1, const float* __restrict__ Wc,
                              const float* __restrict__ W2, const float* __restrict__ Wo,
                              ushort* __restrict__ base) {
    int i = blockIdx.x * 256 + threadIdx.x;  // 0..81919
    const float* src; ushort* hi; ushort* lo; int idx;
    if (i < 16384)      { src = W1; hi = base;          lo = base + 16384;  idx = i; }
    else if (i < 49152) { src = Wc; hi = base + 32768;  lo = base + 65536;  idx = i - 16384; }
    else if (i < 65536) { src = W2; hi = base + 98304;  lo = base + 114688; idx = i - 49152; }
    else                { src = Wo; hi = base + 131072; lo = base + 147456; idx = i - 65536; }
    float f = src[idx];
    ushort hb = f32_to_bf16(f);
    float  hf = bf16_to_f32(hb);
    hi[idx] = hb;
    lo[idx] = f32_to_bf16(f - hf);
}

// ---------------------------------------------------------------------------
// MFMA GEMM: OUT[N][CO] = act(concat(A0,A1)[N][K] @ W^T + bias) (* dis[row])
// W as bf16 hi/lo planes; C = Ahi*Bhi + Ahi*Blo + Alo*Bhi (rel err ~2^-17).
// Block = 4 waves; wave w owns rows [blk*64+w*16, +16) x all CO cols.
// OUTHALF: write fp16 rows (for propagate gather input).
// ---------------------------------------------------------------------------
template <int CO, int K, bool RELU, bool HASBIAS, bool SCALEDIS, bool OUTHALF>
__global__ __launch_bounds__(256) void mfma_gemm(
    const float* __restrict__ A0, const float* __restrict__ A1,
    const ushort* __restrict__ Whi, const ushort* __restrict__ Wlo,
    const float* __restrict__ bias, const float* __restrict__ dis,
    void* __restrict__ outp) {
    constexpr int NF = CO / 16;
    int wave = threadIdx.x >> 6;
    int lane = threadIdx.x & 63;
    int c = lane & 15;        // A row offset / D col offset
    int g = lane >> 4;        // k-group / D row-group
    int row0 = blockIdx.x * 64 + wave * 16;
    int arow = row0 + c;
    int ar = (arow < Nn) ? arow : (Nn - 1);

    f32x4 acc[NF];
    #pragma unroll
    for (int f = 0; f < NF; ++f) acc[f] = (f32x4){0.f, 0.f, 0.f, 0.f};

    #pragma unroll
    for (int ks = 0; ks < K / 32; ++ks) {
        int k0 = ks * 32;
        const float* Asrc = (K == 256 && k0 >= 128) ? A1 : A0;
        int kb = (K == 256 && k0 >= 128) ? (k0 - 128) : k0;
        const float* ap = Asrc + (size_t)ar * 128 + kb + g * 8;
        float4 v0 = *(const float4*)ap;
        float4 v1 = *(const float4*)(ap + 4);
        float vv[8] = {v0.x, v0.y, v0.z, v0.w, v1.x, v1.y, v1.z, v1.w};
        short8 ahi, alo;
        #pragma unroll
        for (int j = 0; j < 8; ++j) {
            float f = vv[j];
            ushort hb = f32_to_bf16(f);
            float  hf = bf16_to_f32(hb);
            ahi[j] = (short)hb;
            alo[j] = (short)f32_to_bf16(f - hf);
        }
        int wk = k0 + g * 8;
        #pragma unroll
        for (int f = 0; f < NF; ++f) {
            size_t widx = (size_t)(f * 16 + c) * K + wk;
            short8 bh = *(const short8*)(Whi + widx);
            short8 bl = *(const short8*)(Wlo + widx);
            acc[f] = __builtin_amdgcn_mfma_f32_16x16x32_bf16(alo, bh, acc[f], 0, 0, 0);
            acc[f] = __builtin_amdgcn_mfma_f32_16x16x32_bf16(ahi, bl, acc[f], 0, 0, 0);
            acc[f] = __builtin_amdgcn_mfma_f32_16x16x32_bf16(ahi, bh, acc[f], 0, 0, 0);
        }
    }

    #pragma unroll
    for (int f = 0; f < NF; ++f) {
        int col = f * 16 + c;
        float bv = HASBIAS ? bias[col] : 0.f;
        #pragma unroll
        for (int rg = 0; rg < 4; ++rg) {
            int row = row0 + g * 4 + rg;
            if (row < Nn) {
                float v = acc[f][rg] + bv;
                if (RELU) v = fmaxf(v, 0.f);
                if (SCALEDIS) v *= dis[row];
                size_t idx = (size_t)row * CO + col;
                if (OUTHALF) ((__half*)outp)[idx] = __float2half_rn(v);
                else         ((float*)outp)[idx]  = v;
            }
        }
    }
}

// ---------------------------------------------------------------------------
// Propagation in g-form, fp16 gather rows (256B/row):
// out[d] = act(dis[d] * (g[d] + sum_{s in N(d)} g[s]) + bias)   [f32 out]
// One 64-lane wave per node, __half2/lane, edge loop unrolled x4 (4 gather
// chains in flight).
// ---------------------------------------------------------------------------
template <bool RELU>
__global__ __launch_bounds__(256) void propagate_kernel(
    const __half* __restrict__ gbuf, const int* __restrict__ offs,
    const int* __restrict__ csr, const float* __restrict__ dis,
    const float* __restrict__ bias, float* __restrict__ out) {
    int node = blockIdx.x * 4 + (threadIdx.x >> 6);
    if (node >= Nn) return;
    int lane = threadIdx.x & 63;
    float2 sv = __half22float2(*((const __half2*)(gbuf + ((size_t)node << 7)) + lane));
    float ax = sv.x, ay = sv.y;
    int beg = offs[node], end = offs[node + 1];
    int e = beg;
    for (; e + 4 <= end; e += 4) {
        int s0 = csr[e], s1 = csr[e + 1], s2 = csr[e + 2], s3 = csr[e + 3];
        __half2 h0 = *((const __half2*)(gbuf + ((size_t)s0 << 7)) + lane);
        __half2 h1 = *((const __half2*)(gbuf + ((size_t)s1 << 7)) + lane);
        __half2 h2 = *((const __half2*)(gbuf + ((size_t)s2 << 7)) + lane);
        __half2 h3 = *((const __half2*)(gbuf + ((size_t)s3 << 7)) + lane);
        float2 v0 = __half22float2(h0), v1 = __half22float2(h1);
        float2 v2 = __half22float2(h2), v3 = __half22float2(h3);
        ax += (v0.x + v1.x) + (v2.x + v3.x);
        ay += (v0.y + v1.y) + (v2.y + v3.y);
    }
    for (; e < end; ++e) {
        int s = csr[e];
        float2 v = __half22float2(*((const __half2*)(gbuf + ((size_t)s << 7)) + lane));
        ax += v.x;
        ay += v.y;
    }
    float di = dis[node];
    ax = fmaf(di, ax, bias[lane * 2]);
    ay = fmaf(di, ay, bias[lane * 2 + 1]);
    if (RELU) { ax = fmaxf(ax, 0.f); ay = fmaxf(ay, 0.f); }
    *((float2*)(out + ((size_t)node << 7)) + lane) = make_float2(ax, ay);
}

// ---------------------------------------------------------------------------

extern "C" void kernel_launch(void* const* d_in, const int* in_sizes, int n_in,
                              void* d_out, int out_size, void* d_ws, size_t ws_size,
                              hipStream_t stream) {
    const float* x  = (const float*)d_in[0];
    const int*   ei = (const int*)d_in[1];   // [2][E]: src then dst
    const float* W1 = (const float*)d_in[2];
    const float* b1 = (const float*)d_in[3];
    const float* Wc = (const float*)d_in[4];
    const float* bc = (const float*)d_in[5];
    const float* W2 = (const float*)d_in[6];
    const float* b2 = (const float*)d_in[7];
    const float* Wo = (const float*)d_in[8];
    const float* bo = (const float*)d_in[9];
    float* out = (float*)d_out;

    // workspace carve-up (256B aligned)
    char* base = (char*)d_ws;
    auto carve = [&](size_t bytes) {
        void* p = (void*)base;
        base += (bytes + 255) & ~(size_t)255;
        return p;
    };
    // tmp region: counts+cursor live during CSR build; W bf16 planes alias it
    // afterwards (planes need 320KB < 400KB of dead counts+cursor space).
    char*  tmp      = (char*)carve(512 * 1024);
    int*   counts   = (int*)tmp;                    // 200000 B
    int*   cursor   = (int*)(tmp + 204800);         // 200000 B
    ushort* wplanes = (ushort*)tmp;                 // 327680 B, used after fill
    int*   offsets  = (int*)carve((Nn + 1) * sizeof(int));
    int*   partials = (int*)carve(256 * sizeof(int));
    float* dis      = (float*)carve(Nn * sizeof(float));
    int*   csr      = (int*)carve(Ee * sizeof(int));
    __half* gbuf    = (__half*)carve((size_t)Nn * 128 * sizeof(__half));  // fp16 g rows
    float* bufB     = (float*)carve((size_t)Nn * 128 * sizeof(float));
    float* bufC     = (float*)carve((size_t)Nn * 128 * sizeof(float));

    const ushort* w1hi = wplanes;
    const ushort* w1lo = wplanes + 16384;
    const ushort* wchi = wplanes + 32768;
    const ushort* wclo = wplanes + 65536;
    const ushort* w2hi = wplanes + 98304;
    const ushort* w2lo = wplanes + 114688;
    const ushort* wohi = wplanes + 131072;
    const ushort* wolo = wplanes + 147456;

    const int SCAN_BLOCKS = (Nn + 255) / 256;  // 196

    // --- CSR build ---
    hipMemsetAsync(counts, 0, Nn * sizeof(int), stream);
    hist_kernel<<<(Ee + 255) / 256, 256, 0, stream>>>(ei + Ee, counts);
    scan1_kernel<<<SCAN_BLOCKS, 256, 0, stream>>>(counts, offsets, partials);
    scan3_kernel<<<SCAN_BLOCKS, 256, 0, stream>>>(offsets, partials, counts, cursor, dis);
    fill_csr_part<<<NPART * 256, 256, 0, stream>>>(ei, cursor, csr);

    // --- weight prep (aliases dead counts/cursor space) ---
    prep_w_kernel<<<320, 256, 0, stream>>>(W1, Wc, W2, Wo, (ushort*)wplanes);

    const int GB = (Nn + 63) / 64;   // 782
    const int PB = (Nn + 3) / 4;     // 12500

    // g1 = fp16( dis * (x @ W1^T) )             -> gbuf
    mfma_gemm<128, 128, false, false, true, true><<<GB, 256, 0, stream>>>(
        x, nullptr, w1hi, w1lo, nullptr, dis, gbuf);
    // x_agg = relu(dis*(sum g1) + b1)           -> bufB (f32)
    propagate_kernel<true><<<PB, 256, 0, stream>>>(gbuf, offsets, csr, dis, b1, bufB);
    // x_comb = relu([x_agg, x] @ Wc^T + bc)     -> bufC (f32)
    mfma_gemm<128, 256, true, true, false, false><<<GB, 256, 0, stream>>>(
        bufB, x, wchi, wclo, bc, nullptr, bufC);
    // g2 = fp16( dis * (x_comb @ W2^T) )        -> gbuf
    mfma_gemm<128, 128, false, false, true, true><<<GB, 256, 0, stream>>>(
        bufC, nullptr, w2hi, w2lo, nullptr, dis, gbuf);
    // agg2 = dis*(sum g2) + b2                  -> bufB (f32)
    propagate_kernel<false><<<PB, 256, 0, stream>>>(gbuf, offsets, csr, dis, b2, bufB);
    // out = [agg2, x_comb] @ Wo^T + bo          -> d_out
    mfma_gemm<64, 256, false, true, false, false><<<GB, 256, 0, stream>>>(
        bufB, bufC, wohi, wolo, bo, nullptr, out);
}

// Round 6
// 485.861 us; speedup vs baseline: 1.4105x; 1.1296x over previous
//
#include <hip/hip_runtime.h>
#include <hip/hip_fp16.h>

// Problem constants (from reference)
#define Nn 50000
#define Ee 1600000
#define INC 128
#define HID 128
#define OUTC 64

typedef __attribute__((ext_vector_type(8))) short short8;
typedef __attribute__((ext_vector_type(4))) float f32x4;
typedef unsigned short ushort;

// ---------------------------------------------------------------------------
// bf16 split helpers (RNE)
// ---------------------------------------------------------------------------
__device__ __forceinline__ ushort f32_to_bf16(float f) {
    unsigned u = __builtin_bit_cast(unsigned, f);
    unsigned r = u + 0x7FFFu + ((u >> 16) & 1u);
    return (ushort)(r >> 16);
}
__device__ __forceinline__ float bf16_to_f32(ushort h) {
    unsigned u = ((unsigned)h) << 16;
    return __builtin_bit_cast(float, u);
}

// ---------------------------------------------------------------------------
// CSR build: hist (returns rank) -> exclusive scan -> atomic-free scatter
// ---------------------------------------------------------------------------

// Histogram that also records each edge's rank within its dst bucket:
// the atomicAdd return value IS the rank. csr fill then needs no atomics.
__global__ void hist_rank_kernel(const int* __restrict__ dst, int* __restrict__ counts,
                                 int* __restrict__ rank) {
    int e = blockIdx.x * blockDim.x + threadIdx.x;
    if (e < Ee) rank[e] = atomicAdd(&counts[dst[e]], 1);
}

__global__ void scan1_kernel(const int* __restrict__ counts, int* __restrict__ offsets,
                             int* __restrict__ partials) {
    __shared__ int sd[256];
    int t = threadIdx.x;
    int i = blockIdx.x * 256 + t;
    int c = (i < Nn) ? counts[i] : 0;
    int v = c;
    #pragma unroll
    for (int off = 1; off < 256; off <<= 1) {
        sd[t] = v; __syncthreads();
        int add = (t >= off) ? sd[t - off] : 0;
        __syncthreads();
        v += add;
    }
    if (i < Nn) offsets[i] = v - c;
    if (t == 255) partials[blockIdx.x] = v;
}

// scan3 with scan2 folded in: every block computes its own base as the sum of
// partials[0..blockIdx.x) (196 values, one per thread, LDS tree-reduce).
__global__ void scan3_kernel(int* __restrict__ offsets, const int* __restrict__ partials,
                             const int* __restrict__ counts, float* __restrict__ dis) {
    __shared__ int sd[256];
    int t = threadIdx.x;
    int s = (t < blockIdx.x) ? partials[t] : 0;   // blockIdx.x <= 195 < 256
    sd[t] = s; __syncthreads();
    #pragma unroll
    for (int off = 128; off > 0; off >>= 1) {
        if (t < off) sd[t] += sd[t + off];
        __syncthreads();
    }
    int base = sd[0];
    int i = blockIdx.x * 256 + t;
    if (i == 0) offsets[Nn] = Ee;
    if (i < Nn) {
        offsets[i] += base;
        dis[i] = rsqrtf((float)(counts[i] + 1));  // +1 self-loop
    }
}

// Atomic-free scatter: pos = offsets[dst] + rank. One edge per thread.
__global__ void fill_csr_rank(const int* __restrict__ ei, const int* __restrict__ rank,
                              const int* __restrict__ offsets, int* __restrict__ csr) {
    int e = blockIdx.x * blockDim.x + threadIdx.x;
    if (e < Ee) {
        int d = ei[Ee + e];
        csr[offsets[d] + rank[e]] = ei[e];
    }
}

// ---------------------------------------------------------------------------
// Weight prep: split all 4 weight matrices into bf16 hi/lo planes.
// ---------------------------------------------------------------------------
__global__ void prep_w_kernel(const float* __restrict__ W1, const float* __restrict__ Wc,
                              const float* __restrict__ W2, const float* __restrict__ Wo,
                              ushort* __restrict__ base) {
    int i = blockIdx.x * 256 + threadIdx.x;  // 0..81919
    const float* src; ushort* hi; ushort* lo; int idx;
    if (i < 16384)      { src = W1; hi = base;          lo = base + 16384;  idx = i; }
    else if (i < 49152) { src = Wc; hi = base + 32768;  lo = base + 65536;  idx = i - 16384; }
    else if (i < 65536) { src = W2; hi = base + 98304;  lo = base + 114688; idx = i - 49152; }
    else                { src = Wo; hi = base + 131072; lo = base + 147456; idx = i - 65536; }
    float f = src[idx];
    ushort hb = f32_to_bf16(f);
    float  hf = bf16_to_f32(hb);
    hi[idx] = hb;
    lo[idx] = f32_to_bf16(f - hf);
}

// ---------------------------------------------------------------------------
// MFMA GEMM: OUT[N][CO] = act(concat(A0,A1)[N][K] @ W^T + bias) (* dis[row])
// W as bf16 hi/lo planes; C = Ahi*Bhi + Ahi*Blo + Alo*Bhi (rel err ~2^-17).
// Block = 4 waves; wave w owns rows [blk*64+w*16, +16) x all CO cols.
// OUTHALF: write fp16 rows (for propagate gather input).
// ---------------------------------------------------------------------------
template <int CO, int K, bool RELU, bool HASBIAS, bool SCALEDIS, bool OUTHALF>
__global__ __launch_bounds__(256) void mfma_gemm(
    const float* __restrict__ A0, const float* __restrict__ A1,
    const ushort* __restrict__ Whi, const ushort* __restrict__ Wlo,
    const float* __restrict__ bias, const float* __restrict__ dis,
    void* __restrict__ outp) {
    constexpr int NF = CO / 16;
    int wave = threadIdx.x >> 6;
    int lane = threadIdx.x & 63;
    int c = lane & 15;        // A row offset / D col offset
    int g = lane >> 4;        // k-group / D row-group
    int row0 = blockIdx.x * 64 + wave * 16;
    int arow = row0 + c;
    int ar = (arow < Nn) ? arow : (Nn - 1);

    f32x4 acc[NF];
    #pragma unroll
    for (int f = 0; f < NF; ++f) acc[f] = (f32x4){0.f, 0.f, 0.f, 0.f};

    #pragma unroll
    for (int ks = 0; ks < K / 32; ++ks) {
        int k0 = ks * 32;
        const float* Asrc = (K == 256 && k0 >= 128) ? A1 : A0;
        int kb = (K == 256 && k0 >= 128) ? (k0 - 128) : k0;
        const float* ap = Asrc + (size_t)ar * 128 + kb + g * 8;
        float4 v0 = *(const float4*)ap;
        float4 v1 = *(const float4*)(ap + 4);
        float vv[8] = {v0.x, v0.y, v0.z, v0.w, v1.x, v1.y, v1.z, v1.w};
        short8 ahi, alo;
        #pragma unroll
        for (int j = 0; j < 8; ++j) {
            float f = vv[j];
            ushort hb = f32_to_bf16(f);
            float  hf = bf16_to_f32(hb);
            ahi[j] = (short)hb;
            alo[j] = (short)f32_to_bf16(f - hf);
        }
        int wk = k0 + g * 8;
        #pragma unroll
        for (int f = 0; f < NF; ++f) {
            size_t widx = (size_t)(f * 16 + c) * K + wk;
            short8 bh = *(const short8*)(Whi + widx);
            short8 bl = *(const short8*)(Wlo + widx);
            acc[f] = __builtin_amdgcn_mfma_f32_16x16x32_bf16(alo, bh, acc[f], 0, 0, 0);
            acc[f] = __builtin_amdgcn_mfma_f32_16x16x32_bf16(ahi, bl, acc[f], 0, 0, 0);
            acc[f] = __builtin_amdgcn_mfma_f32_16x16x32_bf16(ahi, bh, acc[f], 0, 0, 0);
        }
    }

    #pragma unroll
    for (int f = 0; f < NF; ++f) {
        int col = f * 16 + c;
        float bv = HASBIAS ? bias[col] : 0.f;
        #pragma unroll
        for (int rg = 0; rg < 4; ++rg) {
            int row = row0 + g * 4 + rg;
            if (row < Nn) {
                float v = acc[f][rg] + bv;
                if (RELU) v = fmaxf(v, 0.f);
                if (SCALEDIS) v *= dis[row];
                size_t idx = (size_t)row * CO + col;
                if (OUTHALF) ((__half*)outp)[idx] = __float2half_rn(v);
                else         ((float*)outp)[idx]  = v;
            }
        }
    }
}

// ---------------------------------------------------------------------------
// Propagation in g-form, fp16 gather rows (256B/row):
// out[d] = act(dis[d] * (g[d] + sum_{s in N(d)} g[s]) + bias)   [f32 out]
// One 64-lane wave per node, __half2/lane, edge loop unrolled x8 (8 gather
// chains in flight per wave — latency-bound kernel).
// ---------------------------------------------------------------------------
template <bool RELU>
__global__ __launch_bounds__(256) void propagate_kernel(
    const __half* __restrict__ gbuf, const int* __restrict__ offs,
    const int* __restrict__ csr, const float* __restrict__ dis,
    const float* __restrict__ bias, float* __restrict__ out) {
    int node = blockIdx.x * 4 + (threadIdx.x >> 6);
    if (node >= Nn) return;
    int lane = threadIdx.x & 63;
    float2 sv = __half22float2(*((const __half2*)(gbuf + ((size_t)node << 7)) + lane));
    float ax = sv.x, ay = sv.y;
    int beg = offs[node], end = offs[node + 1];
    int e = beg;
    for (; e + 8 <= end; e += 8) {
        int s0 = csr[e],     s1 = csr[e + 1], s2 = csr[e + 2], s3 = csr[e + 3];
        int s4 = csr[e + 4], s5 = csr[e + 5], s6 = csr[e + 6], s7 = csr[e + 7];
        __half2 h0 = *((const __half2*)(gbuf + ((size_t)s0 << 7)) + lane);
        __half2 h1 = *((const __half2*)(gbuf + ((size_t)s1 << 7)) + lane);
        __half2 h2 = *((const __half2*)(gbuf + ((size_t)s2 << 7)) + lane);
        __half2 h3 = *((const __half2*)(gbuf + ((size_t)s3 << 7)) + lane);
        __half2 h4 = *((const __half2*)(gbuf + ((size_t)s4 << 7)) + lane);
        __half2 h5 = *((const __half2*)(gbuf + ((size_t)s5 << 7)) + lane);
        __half2 h6 = *((const __half2*)(gbuf + ((size_t)s6 << 7)) + lane);
        __half2 h7 = *((const __half2*)(gbuf + ((size_t)s7 << 7)) + lane);
        float2 v0 = __half22float2(h0), v1 = __half22float2(h1);
        float2 v2 = __half22float2(h2), v3 = __half22float2(h3);
        float2 v4 = __half22float2(h4), v5 = __half22float2(h5);
        float2 v6 = __half22float2(h6), v7 = __half22float2(h7);
        ax += ((v0.x + v1.x) + (v2.x + v3.x)) + ((v4.x + v5.x) + (v6.x + v7.x));
        ay += ((v0.y + v1.y) + (v2.y + v3.y)) + ((v4.y + v5.y) + (v6.y + v7.y));
    }
    for (; e < end; ++e) {
        int s = csr[e];
        float2 v = __half22float2(*((const __half2*)(gbuf + ((size_t)s << 7)) + lane));
        ax += v.x;
        ay += v.y;
    }
    float di = dis[node];
    ax = fmaf(di, ax, bias[lane * 2]);
    ay = fmaf(di, ay, bias[lane * 2 + 1]);
    if (RELU) { ax = fmaxf(ax, 0.f); ay = fmaxf(ay, 0.f); }
    *((float2*)(out + ((size_t)node << 7)) + lane) = make_float2(ax, ay);
}

// ---------------------------------------------------------------------------

extern "C" void kernel_launch(void* const* d_in, const int* in_sizes, int n_in,
                              void* d_out, int out_size, void* d_ws, size_t ws_size,
                              hipStream_t stream) {
    const float* x  = (const float*)d_in[0];
    const int*   ei = (const int*)d_in[1];   // [2][E]: src then dst
    const float* W1 = (const float*)d_in[2];
    const float* b1 = (const float*)d_in[3];
    const float* Wc = (const float*)d_in[4];
    const float* bc = (const float*)d_in[5];
    const float* W2 = (const float*)d_in[6];
    const float* b2 = (const float*)d_in[7];
    const float* Wo = (const float*)d_in[8];
    const float* bo = (const float*)d_in[9];
    float* out = (float*)d_out;

    // workspace carve-up (256B aligned)
    char* base = (char*)d_ws;
    auto carve = [&](size_t bytes) {
        void* p = (void*)base;
        base += (bytes + 255) & ~(size_t)255;
        return p;
    };
    // tmp region: counts lives during CSR build; W bf16 planes alias it after
    // scan3 (prep_w is launched after fill in stream order).
    char*  tmp      = (char*)carve(512 * 1024);
    int*   counts   = (int*)tmp;                    // 200000 B
    ushort* wplanes = (ushort*)tmp;                 // 327680 B, used after fill
    int*   offsets  = (int*)carve((Nn + 1) * sizeof(int));
    int*   partials = (int*)carve(256 * sizeof(int));
    float* dis      = (float*)carve(Nn * sizeof(float));
    int*   rank     = (int*)carve((size_t)Ee * sizeof(int));
    int*   csr      = (int*)carve((size_t)Ee * sizeof(int));
    __half* gbuf    = (__half*)carve((size_t)Nn * 128 * sizeof(__half));  // fp16 g rows
    float* bufB     = (float*)carve((size_t)Nn * 128 * sizeof(float));
    float* bufC     = (float*)carve((size_t)Nn * 128 * sizeof(float));

    const ushort* w1hi = wplanes;
    const ushort* w1lo = wplanes + 16384;
    const ushort* wchi = wplanes + 32768;
    const ushort* wclo = wplanes + 65536;
    const ushort* w2hi = wplanes + 98304;
    const ushort* w2lo = wplanes + 114688;
    const ushort* wohi = wplanes + 131072;
    const ushort* wolo = wplanes + 147456;

    const int SCAN_BLOCKS = (Nn + 255) / 256;  // 196
    const int EB = (Ee + 255) / 256;           // 6250

    // --- CSR build (atomic-free scatter via rank-from-histogram) ---
    hipMemsetAsync(counts, 0, Nn * sizeof(int), stream);
    hist_rank_kernel<<<EB, 256, 0, stream>>>(ei + Ee, counts, rank);
    scan1_kernel<<<SCAN_BLOCKS, 256, 0, stream>>>(counts, offsets, partials);
    scan3_kernel<<<SCAN_BLOCKS, 256, 0, stream>>>(offsets, partials, counts, dis);
    fill_csr_rank<<<EB, 256, 0, stream>>>(ei, rank, offsets, csr);

    // --- weight prep (aliases dead counts space) ---
    prep_w_kernel<<<320, 256, 0, stream>>>(W1, Wc, W2, Wo, (ushort*)wplanes);

    const int GB = (Nn + 63) / 64;   // 782
    const int PB = (Nn + 3) / 4;     // 12500

    // g1 = fp16( dis * (x @ W1^T) )             -> gbuf
    mfma_gemm<128, 128, false, false, true, true><<<GB, 256, 0, stream>>>(
        x, nullptr, w1hi, w1lo, nullptr, dis, gbuf);
    // x_agg = relu(dis*(sum g1) + b1)           -> bufB (f32)
    propagate_kernel<true><<<PB, 256, 0, stream>>>(gbuf, offsets, csr, dis, b1, bufB);
    // x_comb = relu([x_agg, x] @ Wc^T + bc)     -> bufC (f32)
    mfma_gemm<128, 256, true, true, false, false><<<GB, 256, 0, stream>>>(
        bufB, x, wchi, wclo, bc, nullptr, bufC);
    // g2 = fp16( dis * (x_comb @ W2^T) )        -> gbuf
    mfma_gemm<128, 128, false, false, true, true><<<GB, 256, 0, stream>>>(
        bufC, nullptr, w2hi, w2lo, nullptr, dis, gbuf);
    // agg2 = dis*(sum g2) + b2                  -> bufB (f32)
    propagate_kernel<false><<<PB, 256, 0, stream>>>(gbuf, offsets, csr, dis, b2, bufB);
    // out = [agg2, x_comb] @ Wo^T + bo          -> d_out
    mfma_gemm<64, 256, false, true, false, false><<<GB, 256, 0, stream>>>(
        bufB, bufC, wohi, wolo, bo, nullptr, out);
}